// Round 16
// baseline (385.087 us; speedup 1.0000x reference)
//
#include <hip/hip_runtime.h>

// VQ-VAE vector quantizer, MI355X. N=16384 tokens, D=512, K=8192 codes, f32.
// out0: quantized_st [N*D], out1: vq_loss [N], out2: encoding_inds [N] (as float)
//
// Pass-1: rank codes by int8 dot via mfma_i32_32x32x32_i8 (2x bf16 rate).
// Global scales: x*(127/6), e*(127*8192). 128-token X tile (64KB LDS, grid 256);
// E streamed global->reg (two 4-step quads, deep prefetch); B 4-slot dist-2.
// NEW: selection software-pipelined one ck behind with double-buffered acc
// (select set A during set B's MFMA stream -> no MFMA-drain stall, VALU hides
// in MFMA latency gaps; ck body fully unrolled, no sched_barrier).
// SIGNED sortable key: key = ((dot>>5)<<13) + (8191-code); min/max top-2.
// Pass-2: exact f32-grid reconstruction (numpy-pairwise sums, f64->f32 dot),
// lowest-index tie-break; fused gather/loss. Window 200 trunc-units (=2.9e-4 real).

#define D_DIM   512
#define K_CODES 8192
#define N_TOK   16384

typedef int i32x4  __attribute__((ext_vector_type(4)));
typedef int i32x16 __attribute__((ext_vector_type(16)));

// exact numpy pairwise sum of squares over 512 f32 (serial version, fallback path)
__device__ __forceinline__ float np_pairwise_sq(const float* __restrict__ a) {
    float blk[4];
#pragma unroll
    for (int b = 0; b < 4; ++b) {
        const float* p = a + b * 128;
        float r[8];
#pragma unroll
        for (int j = 0; j < 8; ++j) { double d = (double)p[j]; r[j] = (float)(d * d); }
        for (int i = 8; i < 128; i += 8) {
#pragma unroll
            for (int j = 0; j < 8; ++j) { double d = (double)p[i + j]; r[j] = r[j] + (float)(d * d); }
        }
        blk[b] = ((r[0] + r[1]) + (r[2] + r[3])) + ((r[4] + r[5]) + (r[6] + r[7]));
    }
    return (blk[0] + blk[1]) + (blk[2] + blk[3]);
}

__device__ __forceinline__ unsigned q4pack(float4 v, float sc) {
    int q0 = (int)rintf(fminf(fmaxf(v.x * sc, -127.f), 127.f));
    int q1 = (int)rintf(fminf(fmaxf(v.y * sc, -127.f), 127.f));
    int q2 = (int)rintf(fminf(fmaxf(v.z * sc, -127.f), 127.f));
    int q3 = (int)rintf(fminf(fmaxf(v.w * sc, -127.f), 127.f));
    return (unsigned)(q0 & 255) | ((unsigned)(q1 & 255) << 8)
         | ((unsigned)(q2 & 255) << 16) | ((unsigned)(q3 & 255) << 24);
}

// ---------- prep: int8 fragment-line images + rowsq, one launch ----------
// Xq: [tb 128][line 64 = s*4+tf][lane 64][16B]  (64KB per tb, 8MB)
// Eq: [cb 256][s 16][lane 64][16B]              (4MB)
__global__ __launch_bounds__(256) void vq_prep(
    const float* __restrict__ X, const float* __restrict__ E,
    unsigned char* __restrict__ Xq, unsigned char* __restrict__ Eq,
    float* __restrict__ sx, float* __restrict__ se)
{
    const int bid = blockIdx.x;
    const int t = threadIdx.x;
    if (bid < 2048) {            // X convert
        int tid = bid * 256 + t;
        int tb = tid >> 12, rem = tid & 4095;
        int line = rem >> 6, lane = rem & 63;
        int s = line >> 2, tf = line & 3;
        int token = tb * 128 + tf * 32 + (lane & 31);
        int d0 = s * 32 + (lane >> 5) * 16;
        const float4* p = (const float4*)(X + (size_t)token * D_DIM + d0);
        const float sc = 127.0f / 6.0f;
        uint4 o = make_uint4(q4pack(p[0], sc), q4pack(p[1], sc), q4pack(p[2], sc), q4pack(p[3], sc));
        *(uint4*)(Xq + (size_t)tb * 65536 + (size_t)line * 1024 + (size_t)lane * 16) = o;
    } else if (bid < 3072) {     // E convert
        int tid = (bid - 2048) * 256 + t;
        int cb = tid >> 10, rem = tid & 1023;
        int s = rem >> 6, lane = rem & 63;
        int code = cb * 32 + (lane & 31);
        int d0 = s * 32 + (lane >> 5) * 16;
        const float4* p = (const float4*)(E + (size_t)code * D_DIM + d0);
        const float sc = 1040384.0f;  // 127*8192
        uint4 o = make_uint4(q4pack(p[0], sc), q4pack(p[1], sc), q4pack(p[2], sc), q4pack(p[3], sc));
        *(uint4*)(Eq + (size_t)cb * 16384 + (size_t)s * 1024 + (size_t)lane * 16) = o;
    } else {                     // rowsq (exact numpy-pairwise, 32 lanes per row)
        int wv = (bid - 3072) * 4 + (t >> 6);
        int sub = (t >> 5) & 1, l32 = t & 31;
        int row = wv * 2 + sub;
        const float* p;
        float* dst;
        if (row < N_TOK) { p = X + (size_t)row * D_DIM; dst = sx + row; }
        else if (row < N_TOK + K_CODES) { p = E + (size_t)(row - N_TOK) * D_DIM; dst = se + (row - N_TOK); }
        else return;
        int b = l32 >> 3, rr = l32 & 7;
        const float* q = p + b * 128 + rr;
        double d0 = (double)q[0];
        float r = (float)(d0 * d0);
#pragma unroll
        for (int i = 1; i < 16; ++i) { double d = (double)q[8 * i]; r = r + (float)(d * d); }
#pragma unroll
        for (int m = 1; m <= 16; m <<= 1) r = r + __shfl_xor(r, m);
        if (l32 == 0) *dst = r;
    }
}

#define MFMA8(A, B, C) C = __builtin_amdgcn_mfma_i32_32x32x32_i8(A, B, C, 0, 0, 0)

// streaming top-2 on SIGNED sortable keys
#define UPD(T, P) { int _p = (P); \
    int _mn = _p < m0[T] ? _p : m0[T]; \
    m1[T] = _mn > m1[T] ? _mn : m1[T]; \
    m0[T] = _p > m0[T] ? _p : m0[T]; }

// load 4 tf-frags of LDS line (sidx&15) into slot BS (compile-time offsets)
#define BLOADS(BS, sidx) { \
    BS##0 = *(const i32x4*)(smemB + ((sidx) & 15) * 4096 + laneB); \
    BS##1 = *(const i32x4*)(smemB + ((sidx) & 15) * 4096 + 1024 + laneB); \
    BS##2 = *(const i32x4*)(smemB + ((sidx) & 15) * 4096 + 2048 + laneB); \
    BS##3 = *(const i32x4*)(smemB + ((sidx) & 15) * 4096 + 3072 + laneB); }

// one A-frag x 4 token-frags into acc set (c0..c3)
#define STEPX(Af, BS, c0, c1, c2, c3) { \
    MFMA8(Af, BS##0, c0); MFMA8(Af, BS##1, c1); \
    MFMA8(Af, BS##2, c2); MFMA8(Af, BS##3, c3); }

// full 16-step ck body (straight-line; mid-refills read current Ap)
#define CKBODY(c0, c1, c2, c3) { \
    BLOADS(BC, 2);  STEPX(QA0, BA, c0, c1, c2, c3); \
    BLOADS(BD, 3);  STEPX(QA1, BB, c0, c1, c2, c3); \
    BLOADS(BA, 4);  STEPX(QA2, BC, c0, c1, c2, c3); \
    BLOADS(BB, 5);  STEPX(QA3, BD, c0, c1, c2, c3); \
    QA0 = *(const i32x4*)(Ap + 8  * 1024 + laneB); \
    QA1 = *(const i32x4*)(Ap + 9  * 1024 + laneB); \
    QA2 = *(const i32x4*)(Ap + 10 * 1024 + laneB); \
    QA3 = *(const i32x4*)(Ap + 11 * 1024 + laneB); \
    BLOADS(BC, 6);  STEPX(QB0, BA, c0, c1, c2, c3); \
    BLOADS(BD, 7);  STEPX(QB1, BB, c0, c1, c2, c3); \
    BLOADS(BA, 8);  STEPX(QB2, BC, c0, c1, c2, c3); \
    BLOADS(BB, 9);  STEPX(QB3, BD, c0, c1, c2, c3); \
    QB0 = *(const i32x4*)(Ap + 12 * 1024 + laneB); \
    QB1 = *(const i32x4*)(Ap + 13 * 1024 + laneB); \
    QB2 = *(const i32x4*)(Ap + 14 * 1024 + laneB); \
    QB3 = *(const i32x4*)(Ap + 15 * 1024 + laneB); \
    BLOADS(BC, 10); STEPX(QA0, BA, c0, c1, c2, c3); \
    BLOADS(BD, 11); STEPX(QA1, BB, c0, c1, c2, c3); \
    BLOADS(BA, 12); STEPX(QA2, BC, c0, c1, c2, c3); \
    BLOADS(BB, 13); STEPX(QA3, BD, c0, c1, c2, c3); \
    BLOADS(BC, 14); STEPX(QB0, BA, c0, c1, c2, c3); \
    BLOADS(BD, 15); STEPX(QB1, BB, c0, c1, c2, c3); \
    BLOADS(BA, 0);  STEPX(QB2, BC, c0, c1, c2, c3); \
    BLOADS(BB, 1);  STEPX(QB3, BD, c0, c1, c2, c3); }

// next ck's A prologue (steps 0..7 at Ap+128KB), then advance Ap
#define APROLOGUE() { \
    QA0 = *(const i32x4*)(Ap + 131072 + 0 * 1024 + laneB); \
    QA1 = *(const i32x4*)(Ap + 131072 + 1 * 1024 + laneB); \
    QA2 = *(const i32x4*)(Ap + 131072 + 2 * 1024 + laneB); \
    QA3 = *(const i32x4*)(Ap + 131072 + 3 * 1024 + laneB); \
    QB0 = *(const i32x4*)(Ap + 131072 + 4 * 1024 + laneB); \
    QB1 = *(const i32x4*)(Ap + 131072 + 5 * 1024 + laneB); \
    QB2 = *(const i32x4*)(Ap + 131072 + 6 * 1024 + laneB); \
    QB3 = *(const i32x4*)(Ap + 131072 + 7 * 1024 + laneB); \
    Ap += 131072; }

// select one acc set (one ck behind); binv advances by -256 per ck
#define SELECT(c0, c1, c2, c3) { \
    _Pragma("unroll") \
    for (int g = 0; g < 16; ++g) { \
        const int bp = binv - ((g & 3) + 8 * (g >> 2)); \
        UPD(0, ((c0[g] >> 5) << 13) + bp); \
        UPD(1, ((c1[g] >> 5) << 13) + bp); \
        UPD(2, ((c2[g] >> 5) << 13) + bp); \
        UPD(3, ((c3[g] >> 5) << 13) + bp); \
    } \
    binv -= 256; }

// ---------- pass-1 GEMM: block = 4096 codes (q-half) x 128 tokens, int8 ----------
// Grid 256 = 128 tb x 2 q, XCD-pinned: each XCD's Eq working set is its 2MB q-half.
__global__ __launch_bounds__(512, 2) void vq_gemm(
    const unsigned char* __restrict__ Xq, const unsigned char* __restrict__ Eq,
    float* __restrict__ vbuf, int* __restrict__ ibuf)
{
    __shared__ unsigned int smemU[16384];  // 64 KiB: X int8 fragment lines
    const int tid = threadIdx.x;
    const int lane = tid & 63, w = tid >> 6;
    const int hi5 = lane >> 5, l31 = lane & 31;
    const int laneB = lane * 16;

    const int bid  = blockIdx.x;
    const int xcd  = bid & 7, slot = bid >> 3;   // slot 0..31
    const int q    = xcd >> 2;
    const int tb   = (xcd & 3) * 32 + slot;      // 0..127

    // E base for this wave's first code-block: cb = q*128 + ck*8 + w (16KB per cb)
    const unsigned char* Ap = Eq + (size_t)(q * 128 + w) * 16384;

    // A prologue for ck=0 (global, independent of LDS) issued before X staging
    i32x4 QA0 = *(const i32x4*)(Ap + 0 * 1024 + laneB);
    i32x4 QA1 = *(const i32x4*)(Ap + 1 * 1024 + laneB);
    i32x4 QA2 = *(const i32x4*)(Ap + 2 * 1024 + laneB);
    i32x4 QA3 = *(const i32x4*)(Ap + 3 * 1024 + laneB);
    i32x4 QB0 = *(const i32x4*)(Ap + 4 * 1024 + laneB);
    i32x4 QB1 = *(const i32x4*)(Ap + 5 * 1024 + laneB);
    i32x4 QB2 = *(const i32x4*)(Ap + 6 * 1024 + laneB);
    i32x4 QB3 = *(const i32x4*)(Ap + 7 * 1024 + laneB);

    // stage X block image (64 KiB) linearly into LDS
    {
        const unsigned char* src = Xq + (size_t)tb * 65536;
#pragma unroll
        for (int c = 0; c < 8; ++c) {
            int off  = (c * 512 + tid) * 16;
            int doff = (c * 512 + w * 64) * 16;   // wave-uniform dest base
            __builtin_amdgcn_global_load_lds((const unsigned int*)(src + off),
                                             (unsigned int*)((unsigned char*)smemU + doff), 16, 0, 0);
        }
    }
    __syncthreads();

    const unsigned char* smemB = (const unsigned char*)smemU;

    int m0[4], m1[4];   // packed top-2 signed keys per token-frag
#pragma unroll
    for (int tf = 0; tf < 4; ++tf) { m0[tf] = (int)0x80000000; m1[tf] = (int)0x80000000; }

    // B slots (line & 3 rotation; 16%4==0 -> self-aligning across ck)
    i32x4 BA0, BA1, BA2, BA3, BB0, BB1, BB2, BB3;
    i32x4 BC0, BC1, BC2, BC3, BD0, BD1, BD2, BD3;
    BLOADS(BA, 0);
    BLOADS(BB, 1);

    int binv = 8191 - (q * 4096 + w * 32 + 4 * hi5);  // ck=0 code base inverse

    const i32x16 Z = {};
    i32x16 xa0 = Z, xa1 = Z, xa2 = Z, xa3 = Z;   // acc set A
    i32x16 xb0, xb1, xb2, xb3;                   // acc set B

    // ck=0 into A
    CKBODY(xa0, xa1, xa2, xa3);
    APROLOGUE();                                  // loads ck1, Ap -> ck1

#pragma unroll 1
    for (int it = 0; it < 7; ++it) {
        xb0 = Z; xb1 = Z; xb2 = Z; xb3 = Z;
        CKBODY(xb0, xb1, xb2, xb3);               // ck = 2it+1
        APROLOGUE();                              // loads ck 2it+2
        SELECT(xa0, xa1, xa2, xa3);               // select ck = 2it (no MFMA dep)
        xa0 = Z; xa1 = Z; xa2 = Z; xa3 = Z;
        CKBODY(xa0, xa1, xa2, xa3);               // ck = 2it+2
        APROLOGUE();                              // loads ck 2it+3
        SELECT(xb0, xb1, xb2, xb3);               // select ck = 2it+1
    }
    // A holds ck14 (unselected); Ap points at ck15
    xb0 = Z; xb1 = Z; xb2 = Z; xb3 = Z;
    CKBODY(xb0, xb1, xb2, xb3);                   // ck15 (no prologue)
    SELECT(xa0, xa1, xa2, xa3);                   // ck14
    SELECT(xb0, xb1, xb2, xb3);                   // ck15

#pragma unroll
    for (int tf = 0; tf < 4; ++tf) {
        int token = tb * 128 + tf * 32 + l31;
        int slot2 = q * 32 + w * 4 + hi5 * 2;
        size_t base = (size_t)token * 64 + slot2;
        vbuf[base]     = (float)(m0[tf] >> 13);   // truncated-int dot units (signed)
        ibuf[base]     = 8191 - (m0[tf] & 8191);
        vbuf[base + 1] = (float)(m1[tf] >> 13);
        ibuf[base + 1] = 8191 - (m1[tf] & 8191);
    }
}

// ---------- refine + gather fused: one wave per token ----------
__global__ __launch_bounds__(256) void vq_refine(
    const float* __restrict__ X, const float* __restrict__ E,
    const float* __restrict__ vbuf, const int* __restrict__ ibuf,
    const float* __restrict__ sx, const float* __restrict__ se,
    float* __restrict__ out_idx, float* __restrict__ outq, float* __restrict__ outl)
{
    int t = threadIdx.x;
    int n = blockIdx.x * 4 + (t >> 6);
    int lane = t & 63;

    float v = vbuf[(size_t)n * 64 + lane];
    int   ci = ibuf[(size_t)n * 64 + lane];
    float b0 = v;
#pragma unroll
    for (int m = 1; m <= 32; m <<= 1) b0 = fmaxf(b0, __shfl_xor(b0, m));

    // window 200 trunc-units = 6400 int-units = 2.9e-4 in real-dot units (~12 sigma)
    unsigned long long mask = __ballot(v >= b0 - 200.0f);

    const float* xr = X + (size_t)n * D_DIM;
    float4 xa = ((const float4*)xr)[lane * 2];
    float4 xb = ((const float4*)xr)[lane * 2 + 1];
    float sxn = sx[n];

    float bd = 1e30f; int bi = 2147483647;
    while (mask) {
        int b = (int)__builtin_ctzll(mask);
        mask &= mask - 1;
        int idx = __shfl(ci, b);
        const float* er = E + (size_t)idx * D_DIM;
        float4 ea = ((const float4*)er)[lane * 2];
        float4 eb = ((const float4*)er)[lane * 2 + 1];
        double p = (double)xa.x * ea.x + (double)xa.y * ea.y + (double)xa.z * ea.z + (double)xa.w * ea.w
                 + (double)xb.x * eb.x + (double)xb.y * eb.y + (double)xb.z * eb.z + (double)xb.w * eb.w;
#pragma unroll
        for (int m = 1; m <= 32; m <<= 1) p = p + __shfl_xor(p, m);
        float M = (float)p;
        float S = sxn + se[idx];
        float d = S - 2.0f * M;
        if (d < bd || (d == bd && idx < bi)) { bd = d; bi = idx; }
    }
    if (lane == 0) out_idx[n] = (float)bi;

    // fused gather + loss
    const float* er = E + (size_t)bi * D_DIM;
    float4 ea = ((const float4*)er)[lane * 2];
    float4 eb = ((const float4*)er)[lane * 2 + 1];
    float4 da, db;
    da.x = ea.x - xa.x; da.y = ea.y - xa.y; da.z = ea.z - xa.z; da.w = ea.w - xa.w;
    db.x = eb.x - xb.x; db.y = eb.y - xb.y; db.z = eb.z - xb.z; db.w = eb.w - xb.w;
    float4 qa, qb;
    qa.x = xa.x + da.x; qa.y = xa.y + da.y; qa.z = xa.z + da.z; qa.w = xa.w + da.w;
    qb.x = xb.x + db.x; qb.y = xb.y + db.y; qb.z = xb.z + db.z; qb.w = xb.w + db.w;
    float4* qr = (float4*)(outq + (size_t)n * D_DIM);
    qr[lane * 2] = qa;
    qr[lane * 2 + 1] = qb;
    float s = da.x * da.x + da.y * da.y + da.z * da.z + da.w * da.w
            + db.x * db.x + db.y * db.y + db.z * db.z + db.w * db.w;
#pragma unroll
    for (int m = 1; m <= 32; m <<= 1) s += __shfl_xor(s, m);
    if (lane == 0) {
        float mmean = s * (1.0f / (float)D_DIM);
        outl[n] = mmean + 0.25f * mmean;
    }
}

// ---------- fallback path (proven round-2 kernels, used only if ws too small) ----------
__global__ __launch_bounds__(512) void vq_argmin_fb(
    const float* __restrict__ X, const float* __restrict__ E, float* __restrict__ out_idx)
{
    __shared__ __align__(16) unsigned char smem[48 * 1024];
    float4* Xs = (float4*)smem;
    float4* Es = (float4*)(smem + 16 * 1024);
    float*  cv = (float*)smem;
    int*    ci = (int*)(smem + 16 * 1024);
    const int t = threadIdx.x, tc = t & 31, tr = t >> 5;
    const int tok0 = blockIdx.x * 64;
    const float4* Xg = (const float4*)X;
    const float4* Eg = (const float4*)E;
    float v0[4], v1[4]; int i0[4], i1[4];
#pragma unroll
    for (int i = 0; i < 4; ++i) { v0[i] = -1e30f; v1[i] = -1e30f; i0[i] = 0; i1[i] = 1; }
    for (int kt = 0; kt < K_CODES / 128; ++kt) {
        float acc[4][4];
#pragma unroll
        for (int i = 0; i < 4; ++i)
#pragma unroll
            for (int j = 0; j < 4; ++j) acc[i][j] = 0.f;
        for (int dc = 0; dc < 8; ++dc) {
            __syncthreads();
#pragma unroll
            for (int s = 0; s < 2; ++s) {
                int id = t + s * 512; int rr = id >> 4, m = id & 15;
                Xs[rr * 16 + ((m + (rr >> 2)) & 15)] = Xg[(size_t)(tok0 + rr) * 128 + dc * 16 + m];
            }
#pragma unroll
            for (int s = 0; s < 4; ++s) {
                int id = t + s * 512; int rr = id >> 4, m = id & 15;
                Es[rr * 16 + ((m + (rr >> 2)) & 15)] = Eg[(size_t)(kt * 128 + rr) * 128 + dc * 16 + m];
            }
            __syncthreads();
#pragma unroll
            for (int dd4 = 0; dd4 < 16; ++dd4) {
                float4 xv[4], ev[4];
#pragma unroll
                for (int i = 0; i < 4; ++i) xv[i] = Xs[(4 * tr + i) * 16 + ((dd4 + tr) & 15)];
#pragma unroll
                for (int j = 0; j < 4; ++j) ev[j] = Es[(4 * tc + j) * 16 + ((dd4 + tc) & 15)];
#pragma unroll
                for (int i = 0; i < 4; ++i)
#pragma unroll
                    for (int j = 0; j < 4; ++j)
                        acc[i][j] += xv[i].x * ev[j].x + xv[i].y * ev[j].y + xv[i].z * ev[j].z + xv[i].w * ev[j].w;
            }
        }
#pragma unroll
        for (int i = 0; i < 4; ++i)
#pragma unroll
            for (int j = 0; j < 4; ++j) {
                float v = acc[i][j]; int idx = kt * 128 + 4 * tc + j;
                if (v > v0[i])      { v1[i] = v0[i]; i1[i] = i0[i]; v0[i] = v; i0[i] = idx; }
                else if (v > v1[i]) { v1[i] = v; i1[i] = idx; }
            }
    }
    __syncthreads();
#pragma unroll
    for (int i = 0; i < 4; ++i) {
        int row = 4 * tr + i;
        cv[row * 64 + 2 * tc] = v0[i];     ci[row * 64 + 2 * tc] = i0[i];
        cv[row * 64 + 2 * tc + 1] = v1[i]; ci[row * 64 + 2 * tc + 1] = i1[i];
    }
    __syncthreads();
    if (t < 64) {
        const int row = t;
        float b0 = -1e30f;
        for (int s = 0; s < 64; ++s) b0 = fmaxf(b0, cv[row * 64 + s]);
        const float* xr = X + (size_t)(tok0 + row) * D_DIM;
        const float sumx2 = np_pairwise_sq(xr);
        float bd = 1e30f; int bi = 0x7fffffff;
        for (int s = 0; s < 64; ++s) {
            float v = cv[row * 64 + s];
            if (v < b0 - 1.0e-4f) continue;
            int idx = ci[row * 64 + s];
            const float* er = E + (size_t)idx * D_DIM;
            double acc = 0.0;
            for (int d0 = 0; d0 < D_DIM; ++d0) acc += (double)xr[d0] * (double)er[d0];
            float M = (float)acc;
            float se2 = np_pairwise_sq(er);
            float S = sumx2 + se2;
            float d = S - 2.0f * M;
            if (d < bd || (d == bd && idx < bi)) { bd = d; bi = idx; }
        }
        out_idx[tok0 + row] = (float)bi;
    }
}

__global__ __launch_bounds__(256) void vq_gather_fb(
    const float* __restrict__ X, const float* __restrict__ E,
    const float* __restrict__ idxf, float* __restrict__ outq, float* __restrict__ outl)
{
    const int t = threadIdx.x;
    const int h = t >> 7, tt = t & 127;
    const int n = blockIdx.x * 2 + h;
    const int idx = (int)idxf[n];
    const float4* xr = (const float4*)(X + (size_t)n * D_DIM);
    const float4* er = (const float4*)(E + (size_t)idx * D_DIM);
    float4* qr = (float4*)(outq + (size_t)n * D_DIM);
    float4 x = xr[tt], e = er[tt];
    float4 dl; dl.x = e.x - x.x; dl.y = e.y - x.y; dl.z = e.z - x.z; dl.w = e.w - x.w;
    float4 qv; qv.x = x.x + dl.x; qv.y = x.y + dl.y; qv.z = x.z + dl.z; qv.w = x.w + dl.w;
    qr[tt] = qv;
    float s = dl.x * dl.x + dl.y * dl.y + dl.z * dl.z + dl.w * dl.w;
#pragma unroll
    for (int off = 32; off > 0; off >>= 1) s += __shfl_down(s, off, 64);
    __shared__ float red[4];
    if ((t & 63) == 0) red[t >> 6] = s;
    __syncthreads();
    if (tt == 0) {
        float m = (red[h * 2] + red[h * 2 + 1]) * (1.0f / (float)D_DIM);
        outl[n] = m + 0.25f * m;
    }
}

extern "C" void kernel_launch(void* const* d_in, const int* in_sizes, int n_in,
                              void* d_out, int out_size, void* d_ws, size_t ws_size,
                              hipStream_t stream) {
    const float* X = (const float*)d_in[0];
    const float* E = (const float*)d_in[1];
    float* out  = (float*)d_out;
    float* outq = out;
    float* outl = out + (size_t)N_TOK * D_DIM;
    float* outi = outl + N_TOK;

    const size_t WS_NEED = 21069824;  // Xq 8M + Eq 4M + vbuf 4M + ibuf 4M + sx/se
    if (ws_size >= WS_NEED) {
        unsigned char* ws = (unsigned char*)d_ws;
        unsigned char* Xq = ws;                         // 8MB
        unsigned char* Eq = ws + 8388608;               // 4MB
        float* vbuf = (float*)(ws + 12582912);          // 4MB
        int*   ibuf = (int*)(ws + 16777216);            // 4MB
        float* sx   = (float*)(ws + 20971520);          // 64KB
        float* se   = (float*)(ws + 21037056);          // 32KB
        vq_prep<<<6144, 256, 0, stream>>>(X, E, Xq, Eq, sx, se);
        vq_gemm<<<256, 512, 0, stream>>>(Xq, Eq, vbuf, ibuf);
        vq_refine<<<4096, 256, 0, stream>>>(X, E, vbuf, ibuf, sx, se, outi, outq, outl);
    } else {
        vq_argmin_fb<<<N_TOK / 64, 512, 0, stream>>>(X, E, outi);
        vq_gather_fb<<<8192, 256, 0, stream>>>(X, E, outi, outq, outl);
    }
}

// Round 17
// 122.446 us; speedup vs baseline: 3.1450x; 3.1450x over previous
//
#include <hip/hip_runtime.h>

// VQ-VAE vector quantizer, MI355X. N=16384 tokens, D=512, K=8192 codes, f32.
// out0: quantized_st [N*D], out1: vq_loss [N], out2: encoding_inds [N] (as float)
//
// RESTORED r14 best config (122.3 us total; r15 tile-shrink and r16 acc-dbuf both
// regressed — see session ledger).
// Pass-1: rank codes by int8 dot via mfma_i32_32x32x32_i8 (2x bf16 rate).
// Global scales: x*(127/6), e*(127*8192) -> int dot is monotone approx of real dot,
// err sigma ~2.3e-5 << 2.9e-4 refine window. 128-token X tile in LDS (64KB),
// E streamed global->reg in two 4-step quads (deep prefetch), B 4-slot dist-2,
// cross-ck A prologue under selection. SIGNED sortable key (5 VALU/element):
// key = ((dot>>5)<<13) + (8191-code); v_min_i32/v_max_i32 streaming top-2.
// Pass-2: exact f32-grid reconstruction (numpy-pairwise sums, f64->f32 dot),
// lowest-index tie-break; fused gather/loss. Window 200 trunc-units (=2.9e-4 real).

#define D_DIM   512
#define K_CODES 8192
#define N_TOK   16384

typedef int i32x4  __attribute__((ext_vector_type(4)));
typedef int i32x16 __attribute__((ext_vector_type(16)));

// exact numpy pairwise sum of squares over 512 f32 (serial version, fallback path)
__device__ __forceinline__ float np_pairwise_sq(const float* __restrict__ a) {
    float blk[4];
#pragma unroll
    for (int b = 0; b < 4; ++b) {
        const float* p = a + b * 128;
        float r[8];
#pragma unroll
        for (int j = 0; j < 8; ++j) { double d = (double)p[j]; r[j] = (float)(d * d); }
        for (int i = 8; i < 128; i += 8) {
#pragma unroll
            for (int j = 0; j < 8; ++j) { double d = (double)p[i + j]; r[j] = r[j] + (float)(d * d); }
        }
        blk[b] = ((r[0] + r[1]) + (r[2] + r[3])) + ((r[4] + r[5]) + (r[6] + r[7]));
    }
    return (blk[0] + blk[1]) + (blk[2] + blk[3]);
}

__device__ __forceinline__ unsigned q4pack(float4 v, float sc) {
    int q0 = (int)rintf(fminf(fmaxf(v.x * sc, -127.f), 127.f));
    int q1 = (int)rintf(fminf(fmaxf(v.y * sc, -127.f), 127.f));
    int q2 = (int)rintf(fminf(fmaxf(v.z * sc, -127.f), 127.f));
    int q3 = (int)rintf(fminf(fmaxf(v.w * sc, -127.f), 127.f));
    return (unsigned)(q0 & 255) | ((unsigned)(q1 & 255) << 8)
         | ((unsigned)(q2 & 255) << 16) | ((unsigned)(q3 & 255) << 24);
}

// ---------- prep: int8 fragment-line images + rowsq, one launch ----------
// Xq: [tb 128][line 64 = s*4+tf][lane 64][16B]  (64KB per tb, 8MB)
// Eq: [cb 256][s 16][lane 64][16B]              (4MB)
__global__ __launch_bounds__(256) void vq_prep(
    const float* __restrict__ X, const float* __restrict__ E,
    unsigned char* __restrict__ Xq, unsigned char* __restrict__ Eq,
    float* __restrict__ sx, float* __restrict__ se)
{
    const int bid = blockIdx.x;
    const int t = threadIdx.x;
    if (bid < 2048) {            // X convert
        int tid = bid * 256 + t;
        int tb = tid >> 12, rem = tid & 4095;
        int line = rem >> 6, lane = rem & 63;
        int s = line >> 2, tf = line & 3;
        int token = tb * 128 + tf * 32 + (lane & 31);
        int d0 = s * 32 + (lane >> 5) * 16;
        const float4* p = (const float4*)(X + (size_t)token * D_DIM + d0);
        const float sc = 127.0f / 6.0f;
        uint4 o = make_uint4(q4pack(p[0], sc), q4pack(p[1], sc), q4pack(p[2], sc), q4pack(p[3], sc));
        *(uint4*)(Xq + (size_t)tb * 65536 + (size_t)line * 1024 + (size_t)lane * 16) = o;
    } else if (bid < 3072) {     // E convert
        int tid = (bid - 2048) * 256 + t;
        int cb = tid >> 10, rem = tid & 1023;
        int s = rem >> 6, lane = rem & 63;
        int code = cb * 32 + (lane & 31);
        int d0 = s * 32 + (lane >> 5) * 16;
        const float4* p = (const float4*)(E + (size_t)code * D_DIM + d0);
        const float sc = 1040384.0f;  // 127*8192
        uint4 o = make_uint4(q4pack(p[0], sc), q4pack(p[1], sc), q4pack(p[2], sc), q4pack(p[3], sc));
        *(uint4*)(Eq + (size_t)cb * 16384 + (size_t)s * 1024 + (size_t)lane * 16) = o;
    } else {                     // rowsq (exact numpy-pairwise, 32 lanes per row)
        int wv = (bid - 3072) * 4 + (t >> 6);
        int sub = (t >> 5) & 1, l32 = t & 31;
        int row = wv * 2 + sub;
        const float* p;
        float* dst;
        if (row < N_TOK) { p = X + (size_t)row * D_DIM; dst = sx + row; }
        else if (row < N_TOK + K_CODES) { p = E + (size_t)(row - N_TOK) * D_DIM; dst = se + (row - N_TOK); }
        else return;
        int b = l32 >> 3, rr = l32 & 7;
        const float* q = p + b * 128 + rr;
        double d0 = (double)q[0];
        float r = (float)(d0 * d0);
#pragma unroll
        for (int i = 1; i < 16; ++i) { double d = (double)q[8 * i]; r = r + (float)(d * d); }
#pragma unroll
        for (int m = 1; m <= 16; m <<= 1) r = r + __shfl_xor(r, m);
        if (l32 == 0) *dst = r;
    }
}

#define MFMA8(A, B, C) C = __builtin_amdgcn_mfma_i32_32x32x32_i8(A, B, C, 0, 0, 0)

// streaming top-2 on SIGNED sortable keys: 3 min/max after a 2-op key build
#define UPD(T, P) { int _p = (P); \
    int _mn = _p < m0[T] ? _p : m0[T]; \
    m1[T] = _mn > m1[T] ? _mn : m1[T]; \
    m0[T] = _p > m0[T] ? _p : m0[T]; }

// B-line load: 4 tf-frags of one step (lane-linear, conflict-free); 16 steps wrap
#define BLOAD(d0_, d1_, d2_, d3_, sidx) { int _o = ((sidx) & 15) * 4096 + laneB; \
    d0_ = *(const i32x4*)(smemB + _o); \
    d1_ = *(const i32x4*)(smemB + _o + 1024); \
    d2_ = *(const i32x4*)(smemB + _o + 2048); \
    d3_ = *(const i32x4*)(smemB + _o + 3072); }

#define STEP(Af, B0_, B1_, B2_, B3_) { \
    MFMA8(Af, B0_, a0); MFMA8(Af, B1_, a1); MFMA8(Af, B2_, a2); MFMA8(Af, B3_, a3); }

// ---------- pass-1 GEMM: block = 4096 codes (q-half) x 128 tokens, int8 ----------
// Grid 256 = 128 tb x 2 q, XCD-pinned: each XCD's Eq working set is its 2MB q-half.
__global__ __launch_bounds__(512, 2) void vq_gemm(
    const unsigned char* __restrict__ Xq, const unsigned char* __restrict__ Eq,
    float* __restrict__ vbuf, int* __restrict__ ibuf)
{
    __shared__ unsigned int smemU[16384];  // 64 KiB: X int8 fragment lines
    const int tid = threadIdx.x;
    const int lane = tid & 63, w = tid >> 6;
    const int hi5 = lane >> 5, l31 = lane & 31;
    const int laneB = lane * 16;

    const int bid  = blockIdx.x;
    const int xcd  = bid & 7, slot = bid >> 3;   // slot 0..31
    const int q    = xcd >> 2;
    const int tb   = (xcd & 3) * 32 + slot;      // 0..127

    // E base for this wave's first code-block: cb = q*128 + ck*8 + w (16KB per cb)
    const unsigned char* Ap = Eq + (size_t)(q * 128 + w) * 16384;

    // A prologue (global, independent of LDS) issued before X staging: steps 0..7
    i32x4 QA0 = *(const i32x4*)(Ap + 0 * 1024 + laneB);
    i32x4 QA1 = *(const i32x4*)(Ap + 1 * 1024 + laneB);
    i32x4 QA2 = *(const i32x4*)(Ap + 2 * 1024 + laneB);
    i32x4 QA3 = *(const i32x4*)(Ap + 3 * 1024 + laneB);
    i32x4 QB0 = *(const i32x4*)(Ap + 4 * 1024 + laneB);
    i32x4 QB1 = *(const i32x4*)(Ap + 5 * 1024 + laneB);
    i32x4 QB2 = *(const i32x4*)(Ap + 6 * 1024 + laneB);
    i32x4 QB3 = *(const i32x4*)(Ap + 7 * 1024 + laneB);

    // stage X block image (64 KiB) linearly into LDS
    {
        const unsigned char* src = Xq + (size_t)tb * 65536;
#pragma unroll
        for (int c = 0; c < 8; ++c) {
            int off  = (c * 512 + tid) * 16;
            int doff = (c * 512 + w * 64) * 16;   // wave-uniform dest base
            __builtin_amdgcn_global_load_lds((const unsigned int*)(src + off),
                                             (unsigned int*)((unsigned char*)smemU + doff), 16, 0, 0);
        }
    }
    __syncthreads();

    const unsigned char* smemB = (const unsigned char*)smemU;

    int m0[4], m1[4];   // packed top-2 signed keys per token-frag
#pragma unroll
    for (int tf = 0; tf < 4; ++tf) { m0[tf] = (int)0x80000000; m1[tf] = (int)0x80000000; }

    // B slots: set index == line & 3 (8 steps/mq, self-aligning; 16%4==0 across ck)
    i32x4 BA0, BA1, BA2, BA3, BB0, BB1, BB2, BB3;
    i32x4 BC0, BC1, BC2, BC3, BD0, BD1, BD2, BD3;
    BLOAD(BA0, BA1, BA2, BA3, 0);
    BLOAD(BB0, BB1, BB2, BB3, 1);

#pragma unroll 1
    for (int ck = 0; ck < 16; ++ck) {
        i32x16 a0 = {}, a1 = {}, a2 = {}, a3 = {};

#pragma unroll 1
        for (int mq = 0; mq < 2; ++mq) {
            const int s0 = 8 * mq;
            // quad A: steps s0..s0+3 (B loads at distance 2)
            BLOAD(BC0, BC1, BC2, BC3, s0 + 2); STEP(QA0, BA0, BA1, BA2, BA3);
            BLOAD(BD0, BD1, BD2, BD3, s0 + 3); STEP(QA1, BB0, BB1, BB2, BB3);
            BLOAD(BA0, BA1, BA2, BA3, s0 + 4); STEP(QA2, BC0, BC1, BC2, BC3);
            BLOAD(BB0, BB1, BB2, BB3, s0 + 5); STEP(QA3, BD0, BD1, BD2, BD3);
            if (mq < 1) {  // refill QA <- steps 8..11
                QA0 = *(const i32x4*)(Ap + (size_t)(s0 + 8)  * 1024 + laneB);
                QA1 = *(const i32x4*)(Ap + (size_t)(s0 + 9)  * 1024 + laneB);
                QA2 = *(const i32x4*)(Ap + (size_t)(s0 + 10) * 1024 + laneB);
                QA3 = *(const i32x4*)(Ap + (size_t)(s0 + 11) * 1024 + laneB);
            }
            // quad B: steps s0+4..s0+7
            BLOAD(BC0, BC1, BC2, BC3, s0 + 6); STEP(QB0, BA0, BA1, BA2, BA3);
            BLOAD(BD0, BD1, BD2, BD3, s0 + 7); STEP(QB1, BB0, BB1, BB2, BB3);
            BLOAD(BA0, BA1, BA2, BA3, s0 + 8); STEP(QB2, BC0, BC1, BC2, BC3);
            BLOAD(BB0, BB1, BB2, BB3, s0 + 9); STEP(QB3, BD0, BD1, BD2, BD3);
            if (mq < 1) {  // refill QB <- steps 12..15
                QB0 = *(const i32x4*)(Ap + (size_t)(s0 + 12) * 1024 + laneB);
                QB1 = *(const i32x4*)(Ap + (size_t)(s0 + 13) * 1024 + laneB);
                QB2 = *(const i32x4*)(Ap + (size_t)(s0 + 14) * 1024 + laneB);
                QB3 = *(const i32x4*)(Ap + (size_t)(s0 + 15) * 1024 + laneB);
            }
        }
        // (mq=1 tail BLOADs wrapped to lines 0,1 -> slots BA,BB primed for next ck)

        // next ck's A prologue BEFORE the selection burst (latency hidden under it)
        const unsigned char* Apn = Ap + 131072;   // +8 code-blocks
        if (ck < 15) {
            QA0 = *(const i32x4*)(Apn + 0 * 1024 + laneB);
            QA1 = *(const i32x4*)(Apn + 1 * 1024 + laneB);
            QA2 = *(const i32x4*)(Apn + 2 * 1024 + laneB);
            QA3 = *(const i32x4*)(Apn + 3 * 1024 + laneB);
            QB0 = *(const i32x4*)(Apn + 4 * 1024 + laneB);
            QB1 = *(const i32x4*)(Apn + 5 * 1024 + laneB);
            QB2 = *(const i32x4*)(Apn + 6 * 1024 + laneB);
            QB3 = *(const i32x4*)(Apn + 7 * 1024 + laneB);
        }
        __builtin_amdgcn_sched_barrier(0);

        // SIGNED key top-2: key = ((dot>>5)<<13) + bp. |dot| < 2^23 -> |key| < 2^31.
        // Keys are distinct within a stream (bp unique per code) -> no tie ambiguity;
        // equal truncated dots resolve to lower code via larger bp under signed max.
        const int cb = q * 128 + ck * 8 + w;
        const int binv = 8191 - (cb * 32 + 4 * hi5);
#pragma unroll
        for (int g = 0; g < 16; ++g) {
            const int bp = binv - ((g & 3) + 8 * (g >> 2));
            UPD(0, ((a0[g] >> 5) << 13) + bp);
            UPD(1, ((a1[g] >> 5) << 13) + bp);
            UPD(2, ((a2[g] >> 5) << 13) + bp);
            UPD(3, ((a3[g] >> 5) << 13) + bp);
        }
        Ap = Apn;
    }

#pragma unroll
    for (int tf = 0; tf < 4; ++tf) {
        int token = tb * 128 + tf * 32 + l31;
        int slot2 = q * 32 + w * 4 + hi5 * 2;
        size_t base = (size_t)token * 64 + slot2;
        vbuf[base]     = (float)(m0[tf] >> 13);          // truncated-int dot units (signed)
        ibuf[base]     = 8191 - (m0[tf] & 8191);
        vbuf[base + 1] = (float)(m1[tf] >> 13);
        ibuf[base + 1] = 8191 - (m1[tf] & 8191);
    }
}

// ---------- refine + gather fused: one wave per token ----------
__global__ __launch_bounds__(256) void vq_refine(
    const float* __restrict__ X, const float* __restrict__ E,
    const float* __restrict__ vbuf, const int* __restrict__ ibuf,
    const float* __restrict__ sx, const float* __restrict__ se,
    float* __restrict__ out_idx, float* __restrict__ outq, float* __restrict__ outl)
{
    int t = threadIdx.x;
    int n = blockIdx.x * 4 + (t >> 6);
    int lane = t & 63;

    float v = vbuf[(size_t)n * 64 + lane];
    int   ci = ibuf[(size_t)n * 64 + lane];
    float b0 = v;
#pragma unroll
    for (int m = 1; m <= 32; m <<= 1) b0 = fmaxf(b0, __shfl_xor(b0, m));

    // window 200 trunc-units = 6400 int-units = 2.9e-4 in real-dot units (~12 sigma)
    unsigned long long mask = __ballot(v >= b0 - 200.0f);

    const float* xr = X + (size_t)n * D_DIM;
    float4 xa = ((const float4*)xr)[lane * 2];
    float4 xb = ((const float4*)xr)[lane * 2 + 1];
    float sxn = sx[n];

    float bd = 1e30f; int bi = 2147483647;
    while (mask) {
        int b = (int)__builtin_ctzll(mask);
        mask &= mask - 1;
        int idx = __shfl(ci, b);
        const float* er = E + (size_t)idx * D_DIM;
        float4 ea = ((const float4*)er)[lane * 2];
        float4 eb = ((const float4*)er)[lane * 2 + 1];
        double p = (double)xa.x * ea.x + (double)xa.y * ea.y + (double)xa.z * ea.z + (double)xa.w * ea.w
                 + (double)xb.x * eb.x + (double)xb.y * eb.y + (double)xb.z * eb.z + (double)xb.w * eb.w;
#pragma unroll
        for (int m = 1; m <= 32; m <<= 1) p = p + __shfl_xor(p, m);
        float M = (float)p;
        float S = sxn + se[idx];
        float d = S - 2.0f * M;
        if (d < bd || (d == bd && idx < bi)) { bd = d; bi = idx; }
    }
    if (lane == 0) out_idx[n] = (float)bi;

    // fused gather + loss
    const float* er = E + (size_t)bi * D_DIM;
    float4 ea = ((const float4*)er)[lane * 2];
    float4 eb = ((const float4*)er)[lane * 2 + 1];
    float4 da, db;
    da.x = ea.x - xa.x; da.y = ea.y - xa.y; da.z = ea.z - xa.z; da.w = ea.w - xa.w;
    db.x = eb.x - xb.x; db.y = eb.y - xb.y; db.z = eb.z - xb.z; db.w = eb.w - xb.w;
    float4 qa, qb;
    qa.x = xa.x + da.x; qa.y = xa.y + da.y; qa.z = xa.z + da.z; qa.w = xa.w + da.w;
    qb.x = xb.x + db.x; qb.y = xb.y + db.y; qb.z = xb.z + db.z; qb.w = xb.w + db.w;
    float4* qr = (float4*)(outq + (size_t)n * D_DIM);
    qr[lane * 2] = qa;
    qr[lane * 2 + 1] = qb;
    float s = da.x * da.x + da.y * da.y + da.z * da.z + da.w * da.w
            + db.x * db.x + db.y * db.y + db.z * db.z + db.w * db.w;
#pragma unroll
    for (int m = 1; m <= 32; m <<= 1) s += __shfl_xor(s, m);
    if (lane == 0) {
        float mmean = s * (1.0f / (float)D_DIM);
        outl[n] = mmean + 0.25f * mmean;
    }
}

// ---------- fallback path (proven round-2 kernels, used only if ws too small) ----------
__global__ __launch_bounds__(512) void vq_argmin_fb(
    const float* __restrict__ X, const float* __restrict__ E, float* __restrict__ out_idx)
{
    __shared__ __align__(16) unsigned char smem[48 * 1024];
    float4* Xs = (float4*)smem;
    float4* Es = (float4*)(smem + 16 * 1024);
    float*  cv = (float*)smem;
    int*    ci = (int*)(smem + 16 * 1024);
    const int t = threadIdx.x, tc = t & 31, tr = t >> 5;
    const int tok0 = blockIdx.x * 64;
    const float4* Xg = (const float4*)X;
    const float4* Eg = (const float4*)E;
    float v0[4], v1[4]; int i0[4], i1[4];
#pragma unroll
    for (int i = 0; i < 4; ++i) { v0[i] = -1e30f; v1[i] = -1e30f; i0[i] = 0; i1[i] = 1; }
    for (int kt = 0; kt < K_CODES / 128; ++kt) {
        float acc[4][4];
#pragma unroll
        for (int i = 0; i < 4; ++i)
#pragma unroll
            for (int j = 0; j < 4; ++j) acc[i][j] = 0.f;
        for (int dc = 0; dc < 8; ++dc) {
            __syncthreads();
#pragma unroll
            for (int s = 0; s < 2; ++s) {
                int id = t + s * 512; int rr = id >> 4, m = id & 15;
                Xs[rr * 16 + ((m + (rr >> 2)) & 15)] = Xg[(size_t)(tok0 + rr) * 128 + dc * 16 + m];
            }
#pragma unroll
            for (int s = 0; s < 4; ++s) {
                int id = t + s * 512; int rr = id >> 4, m = id & 15;
                Es[rr * 16 + ((m + (rr >> 2)) & 15)] = Eg[(size_t)(kt * 128 + rr) * 128 + dc * 16 + m];
            }
            __syncthreads();
#pragma unroll
            for (int dd4 = 0; dd4 < 16; ++dd4) {
                float4 xv[4], ev[4];
#pragma unroll
                for (int i = 0; i < 4; ++i) xv[i] = Xs[(4 * tr + i) * 16 + ((dd4 + tr) & 15)];
#pragma unroll
                for (int j = 0; j < 4; ++j) ev[j] = Es[(4 * tc + j) * 16 + ((dd4 + tc) & 15)];
#pragma unroll
                for (int i = 0; i < 4; ++i)
#pragma unroll
                    for (int j = 0; j < 4; ++j)
                        acc[i][j] += xv[i].x * ev[j].x + xv[i].y * ev[j].y + xv[i].z * ev[j].z + xv[i].w * ev[j].w;
            }
        }
#pragma unroll
        for (int i = 0; i < 4; ++i)
#pragma unroll
            for (int j = 0; j < 4; ++j) {
                float v = acc[i][j]; int idx = kt * 128 + 4 * tc + j;
                if (v > v0[i])      { v1[i] = v0[i]; i1[i] = i0[i]; v0[i] = v; i0[i] = idx; }
                else if (v > v1[i]) { v1[i] = v; i1[i] = idx; }
            }
    }
    __syncthreads();
#pragma unroll
    for (int i = 0; i < 4; ++i) {
        int row = 4 * tr + i;
        cv[row * 64 + 2 * tc] = v0[i];     ci[row * 64 + 2 * tc] = i0[i];
        cv[row * 64 + 2 * tc + 1] = v1[i]; ci[row * 64 + 2 * tc + 1] = i1[i];
    }
    __syncthreads();
    if (t < 64) {
        const int row = t;
        float b0 = -1e30f;
        for (int s = 0; s < 64; ++s) b0 = fmaxf(b0, cv[row * 64 + s]);
        const float* xr = X + (size_t)(tok0 + row) * D_DIM;
        const float sumx2 = np_pairwise_sq(xr);
        float bd = 1e30f; int bi = 0x7fffffff;
        for (int s = 0; s < 64; ++s) {
            float v = cv[row * 64 + s];
            if (v < b0 - 1.0e-4f) continue;
            int idx = ci[row * 64 + s];
            const float* er = E + (size_t)idx * D_DIM;
            double acc = 0.0;
            for (int d0 = 0; d0 < D_DIM; ++d0) acc += (double)xr[d0] * (double)er[d0];
            float M = (float)acc;
            float se2 = np_pairwise_sq(er);
            float S = sumx2 + se2;
            float d = S - 2.0f * M;
            if (d < bd || (d == bd && idx < bi)) { bd = d; bi = idx; }
        }
        out_idx[tok0 + row] = (float)bi;
    }
}

__global__ __launch_bounds__(256) void vq_gather_fb(
    const float* __restrict__ X, const float* __restrict__ E,
    const float* __restrict__ idxf, float* __restrict__ outq, float* __restrict__ outl)
{
    const int t = threadIdx.x;
    const int h = t >> 7, tt = t & 127;
    const int n = blockIdx.x * 2 + h;
    const int idx = (int)idxf[n];
    const float4* xr = (const float4*)(X + (size_t)n * D_DIM);
    const float4* er = (const float4*)(E + (size_t)idx * D_DIM);
    float4* qr = (float4*)(outq + (size_t)n * D_DIM);
    float4 x = xr[tt], e = er[tt];
    float4 dl; dl.x = e.x - x.x; dl.y = e.y - x.y; dl.z = e.z - x.z; dl.w = e.w - x.w;
    float4 qv; qv.x = x.x + dl.x; qv.y = x.y + dl.y; qv.z = x.z + dl.z; qv.w = x.w + dl.w;
    qr[tt] = qv;
    float s = dl.x * dl.x + dl.y * dl.y + dl.z * dl.z + dl.w * dl.w;
#pragma unroll
    for (int off = 32; off > 0; off >>= 1) s += __shfl_down(s, off, 64);
    __shared__ float red[4];
    if ((t & 63) == 0) red[t >> 6] = s;
    __syncthreads();
    if (tt == 0) {
        float m = (red[h * 2] + red[h * 2 + 1]) * (1.0f / (float)D_DIM);
        outl[n] = m + 0.25f * m;
    }
}

extern "C" void kernel_launch(void* const* d_in, const int* in_sizes, int n_in,
                              void* d_out, int out_size, void* d_ws, size_t ws_size,
                              hipStream_t stream) {
    const float* X = (const float*)d_in[0];
    const float* E = (const float*)d_in[1];
    float* out  = (float*)d_out;
    float* outq = out;
    float* outl = out + (size_t)N_TOK * D_DIM;
    float* outi = outl + N_TOK;

    const size_t WS_NEED = 21069824;  // Xq 8M + Eq 4M + vbuf 4M + ibuf 4M + sx/se
    if (ws_size >= WS_NEED) {
        unsigned char* ws = (unsigned char*)d_ws;
        unsigned char* Xq = ws;                         // 8MB
        unsigned char* Eq = ws + 8388608;               // 4MB
        float* vbuf = (float*)(ws + 12582912);          // 4MB
        int*   ibuf = (int*)(ws + 16777216);            // 4MB
        float* sx   = (float*)(ws + 20971520);          // 64KB
        float* se   = (float*)(ws + 21037056);          // 32KB
        vq_prep<<<6144, 256, 0, stream>>>(X, E, Xq, Eq, sx, se);
        vq_gemm<<<256, 512, 0, stream>>>(Xq, Eq, vbuf, ibuf);
        vq_refine<<<4096, 256, 0, stream>>>(X, E, vbuf, ibuf, sx, se, outi, outq, outl);
    } else {
        vq_argmin_fb<<<N_TOK / 64, 512, 0, stream>>>(X, E, outi);
        vq_gather_fb<<<8192, 256, 0, stream>>>(X, E, outi, outq, outl);
    }
}